// Round 6
// baseline (579.160 us; speedup 1.0000x reference)
//
#include <hip/hip_runtime.h>
#include <hip/hip_bf16.h>
#include <math.h>

typedef unsigned short u16;
typedef unsigned int u32;
typedef __attribute__((ext_vector_type(8))) __bf16 bf16x8;
typedef __attribute__((ext_vector_type(4))) float f32x4;
typedef __attribute__((ext_vector_type(4))) u32 u32x4;
typedef __attribute__((ext_vector_type(2))) u32 u32x2;

#define NNODES 50000
#define NEDGES 800000

__device__ __forceinline__ float bf2f(u16 u) {
    union { u32 i; float f; } v; v.i = ((u32)u) << 16; return v.f;
}
__device__ __forceinline__ u16 f2bf(float x) {
    union { float f; u32 i; } v; v.f = x;
    u32 r = v.i + 0x7fffu + ((v.i >> 16) & 1u);
    return (u16)(r >> 16);
}
__device__ __forceinline__ float lrelu(float x) { return x >= 0.f ? x : 0.2f * x; }

// async global->LDS 16B (direct DMA, no VGPR round trip)
__device__ __forceinline__ void gload_lds16(const u16* g, u16* l) {
    __builtin_amdgcn_global_load_lds((const __attribute__((address_space(1))) u32*)g,
                                     (__attribute__((address_space(3))) u32*)l, 16, 0, 0);
}

// ---------------- CSR build ----------------
__global__ __launch_bounds__(256) void k_zero2(int* a, int* b, int count) {
    int i = blockIdx.x * 256 + threadIdx.x;
    if (i < count) { a[i] = 0; b[i] = 0; }
}

__global__ __launch_bounds__(256) void k_count(const int* __restrict__ dst, int* __restrict__ counts, int e) {
    int i = blockIdx.x * 256 + threadIdx.x;
    if (i < e) atomicAdd(&counts[dst[i]], 1);
}

__global__ __launch_bounds__(256) void k_scan1(const int* __restrict__ counts, int* __restrict__ row_ptr,
                                               int* __restrict__ bsums, int n) {
    __shared__ int tmp[256];
    int t = threadIdx.x, i = blockIdx.x * 256 + t;
    int v = (i < n) ? counts[i] : 0;
    tmp[t] = v; __syncthreads();
    for (int off = 1; off < 256; off <<= 1) {
        int x = 0; if (t >= off) x = tmp[t - off];
        __syncthreads(); tmp[t] += x; __syncthreads();
    }
    if (i < n) row_ptr[i] = tmp[t] - v;
    if (t == 255) bsums[blockIdx.x] = tmp[255];
}

__global__ __launch_bounds__(256) void k_scan2(int* bsums, int nb) {
    __shared__ int tmp[256];
    int t = threadIdx.x;
    int v = (t < nb) ? bsums[t] : 0;
    tmp[t] = v; __syncthreads();
    for (int off = 1; off < 256; off <<= 1) {
        int x = 0; if (t >= off) x = tmp[t - off];
        __syncthreads(); tmp[t] += x; __syncthreads();
    }
    if (t < nb) bsums[t] = tmp[t] - v;
}

__global__ __launch_bounds__(256) void k_scan3(int* __restrict__ row_ptr, const int* __restrict__ bsums,
                                               int n, int total) {
    int i = blockIdx.x * 256 + threadIdx.x;
    if (i < n) row_ptr[i] += bsums[blockIdx.x];
    if (i == 0) row_ptr[n] = total;
}

__global__ __launch_bounds__(256) void k_fill(const int* __restrict__ src, const int* __restrict__ dst,
                                              const int* __restrict__ row_ptr, int* __restrict__ cursor,
                                              int* __restrict__ esrc, int e) {
    int i = blockIdx.x * 256 + threadIdx.x;
    if (i < e) {
        int d = dst[i];
        int p = row_ptr[d] + atomicAdd(&cursor[d], 1);
        esrc[p] = src[i];
    }
}

// ---------------- fused weight prep ----------------
__global__ __launch_bounds__(256) void k_prep(const float* __restrict__ W1, const float* __restrict__ W2,
                                              const float* __restrict__ Wm, const float* __restrict__ Wv,
                                              const float* __restrict__ al2, const float* __restrict__ ar2,
                                              const float* __restrict__ b2,
                                              u16* __restrict__ W1t, u16* __restrict__ Wct,
                                              u16* __restrict__ Bmvt,
                                              float* __restrict__ ul, float* __restrict__ ur,
                                              float* __restrict__ bmean) {
    int b = blockIdx.x, t = threadIdx.x;
    if (b < 500) {
        int i = b * 256 + t;           // i < 128000
        int k = i >> 7, n = i & 127;
        W1t[(size_t)n * 1000 + k] = f2bf(W1[i]);
    } else if (b < 628) {
        int i = (b - 500) * 256 + t;   // i < 32768
        int f = i >> 8, c = i & 255, h = c >> 7, k = c & 127;
        Wct[i] = f2bf(0.5f * W2[(size_t)k * 256 + h * 128 + f]);
    } else if (b == 628) {
        int h = t >> 7, k = t & 127;
        const float* wrow = W2 + (size_t)k * 256 + h * 128;
        const float* alh = al2 + h * 128;
        const float* arh = ar2 + h * 128;
        float sl = 0.f, sr = 0.f;
        for (int f = 0; f < 128; f += 4) {
            f32x4 w = *(const f32x4*)(wrow + f);
            f32x4 a = *(const f32x4*)(alh + f);
            f32x4 r = *(const f32x4*)(arh + f);
#pragma unroll
            for (int q = 0; q < 4; q++) { sl += w[q] * a[q]; sr += w[q] * r[q]; }
        }
        ul[t] = sl; ur[t] = sr;
        if (t < 128) bmean[t] = 0.5f * (b2[t] + b2[128 + t]);
    } else {
        for (int i = t; i < 64 * 128; i += 256) {
            int c = i >> 7, k = i & 127;
            Bmvt[i] = f2bf(c < 32 ? Wm[(size_t)k * 32 + c] : Wv[(size_t)k * 32 + (c - 32)]);
        }
    }
}

// ---------------- A-fragment loaders (f32 or bf16 source) ----------------
__device__ __forceinline__ void load_af(const float* __restrict__ arow, int k0, int K, bf16x8& a) {
    if (k0 + 8 <= K) {
        f32x4 a0 = *(const f32x4*)(arow + k0);
        f32x4 a1 = *(const f32x4*)(arow + k0 + 4);
#pragma unroll
        for (int j = 0; j < 4; j++) { a[j] = (__bf16)a0[j]; a[4 + j] = (__bf16)a1[j]; }
    } else {
#pragma unroll
        for (int j = 0; j < 8; j++) a[j] = (__bf16)0.f;
    }
}
__device__ __forceinline__ void load_af(const u16* __restrict__ arow, int k0, int K, bf16x8& a) {
    if (k0 + 8 <= K) a = *(const bf16x8*)(arow + k0);
    else {
#pragma unroll
        for (int j = 0; j < 8; j++) a[j] = (__bf16)0.f;
    }
}

// ---------------- K-chunked MFMA GEMM: C[M,128](bf16) = A[M,K] * Bt[128,K]^T ----------------
// Stage a 256-wide K-chunk of B (all 128 cols, 64KB LDS, granule layout [g][col][8],
// measured conflict-free) + prefetch all 8 A-frags for the chunk, ONE barrier, then 8 MFMA
// k-steps from LDS/registers, one trailing barrier. Drain paid 4x/block instead of 32x.
// 64KB LDS -> 2 blocks/CU so one block's stage overlaps the other's compute.
// K-tail (K=1000, chunk 3): granules with kq>=K are skipped -> stale-but-finite LDS; the
// matching A-frags are zeroed by load_af, so those products contribute exactly 0.
// MODE 0: layer-1 — also emit el/er attention projections from f32 accumulators.
// MODE 1: layer-2 — C = f2bf(acc + bias[col] + bf2f(resid[row*128+col]))
template <typename AT, int MODE>
__global__ __launch_bounds__(256) void k_gemm_tiled(const AT* __restrict__ A, const u16* __restrict__ Bt,
                                                    u16* __restrict__ C, int M, int Nn, int K,
                                                    const float* __restrict__ bias,
                                                    const u16* __restrict__ resid,
                                                    const float* __restrict__ al,
                                                    const float* __restrict__ ar,
                                                    float* __restrict__ el, float* __restrict__ er) {
    __shared__ __align__(16) u16 lb[32 * 128 * 8];   // 64KB: [granule g<32][col<128][8]
    const int tid = threadIdx.x;
    const int wave = tid >> 6, lane = tid & 63;
    const int m = lane & 15, quad = lane >> 4;
    const int row0 = blockIdx.x * 64 + wave * 16;

    f32x4 acc[8];
#pragma unroll
    for (int t = 0; t < 8; t++)
#pragma unroll
        for (int r = 0; r < 4; r++) acc[t][r] = 0.f;

    int arr = row0 + m; if (arr > M - 1) arr = M - 1;  // clamp OOB rows (stores guarded)
    const AT* arow = A + (size_t)arr * K;
    // staging: thread covers col = tid&127, granules it*2 + (tid>>7), it in [0,16)
    const int scol = tid & 127, shi = tid >> 7;
    const u16* bcol = Bt + (size_t)scol * K;
    u16* sdst = &lb[((size_t)shi * 128 + scol) * 8];   // +it*2048 u16 per iteration

    const int KC = 256;
    const int nchunks = (K + KC - 1) / KC;
    bf16x8 afr[8];

    for (int c = 0; c < nchunks; ++c) {
        const int kb = c * KC;
        // A first (longest latency), then B stage — all drain at the barrier together
#pragma unroll
        for (int ks = 0; ks < 8; ++ks)
            load_af(arow, kb + ks * 32 + quad * 8, K, afr[ks]);
#pragma unroll
        for (int it = 0; it < 16; ++it) {
            int kq = kb + (it * 2 + shi) * 8;
            if (kq < K) gload_lds16(bcol + kq, sdst + it * 2048);
        }
        __syncthreads();
        // 8 k-steps straight out of LDS + registers (no drains inside)
#pragma unroll
        for (int ks = 0; ks < 8; ++ks) {
#pragma unroll
            for (int t = 0; t < 8; ++t) {
                bf16x8 b = *(const bf16x8*)&lb[((ks * 4 + quad) * 128 + t * 16 + m) * 8];
                acc[t] = __builtin_amdgcn_mfma_f32_16x16x32_bf16(afr[ks], b, acc[t], 0, 0, 0);
            }
        }
        __syncthreads();
    }

#pragma unroll
    for (int r = 0; r < 4; r++) {
        int row = row0 + quad * 4 + r;
        if (MODE == 0) {
            float pe = 0.f, pr = 0.f;
#pragma unroll
            for (int t = 0; t < 8; t++) {
                float a = acc[t][r];
                int c = t * 16 + m;
                pe += a * al[c]; pr += a * ar[c];
            }
#pragma unroll
            for (int off = 8; off; off >>= 1) { pe += __shfl_xor(pe, off); pr += __shfl_xor(pr, off); }
            if (m == 0 && row < M) { el[row] = pe; er[row] = pr; }
        }
#pragma unroll
        for (int t = 0; t < 8; t++) {
            int col = t * 16 + m;
            if (row < M) {
                float v = acc[t][r];
                if (MODE == 1) v += bias[col] + bf2f(resid[(size_t)row * Nn + col]);
                C[(size_t)row * Nn + col] = f2bf(v);
            }
        }
    }
}

// ---------------- fused mean/var GEMM: [N,128] x [128,64] ([Wm|Wv] combined) ----------------
__global__ __launch_bounds__(64) void k_gemmmv(const u16* __restrict__ A, const u16* __restrict__ Bt,
                                               u16* __restrict__ featmv,
                                               const float* __restrict__ alm, const float* __restrict__ arm,
                                               const float* __restrict__ alv, const float* __restrict__ arv,
                                               float* __restrict__ elm, float* __restrict__ erm,
                                               float* __restrict__ elv, float* __restrict__ erv, int M) {
    int row0 = blockIdx.x * 16;
    int lane = threadIdx.x;
    int m = lane & 15, quad = lane >> 4;
    f32x4 acc[4];
#pragma unroll
    for (int t = 0; t < 4; t++)
#pragma unroll
        for (int r = 0; r < 4; r++) acc[t][r] = 0.f;

    const u16* arow = A + (size_t)(row0 + m) * 128 + quad * 8;
#pragma unroll
    for (int s = 0; s < 4; ++s) {
        bf16x8 a = *(const bf16x8*)(arow + s * 32);
#pragma unroll
        for (int t = 0; t < 4; t++) {
            bf16x8 b = *(const bf16x8*)(Bt + (size_t)(t * 16 + m) * 128 + s * 32 + quad * 8);
            acc[t] = __builtin_amdgcn_mfma_f32_16x16x32_bf16(a, b, acc[t], 0, 0, 0);
        }
    }
#pragma unroll
    for (int r = 0; r < 4; r++) {
        int row = row0 + quad * 4 + r;
#pragma unroll
        for (int t = 0; t < 4; t++) {
            float a = acc[t][r];
            const float* alp = (t < 2) ? alm : alv;
            const float* arp = (t < 2) ? arm : arv;
            float pe = a * alp[(t & 1) * 16 + m];
            float pr = a * arp[(t & 1) * 16 + m];
#pragma unroll
            for (int off = 8; off; off >>= 1) { pe += __shfl_xor(pe, off); pr += __shfl_xor(pr, off); }
            if (m == 0 && row < M) {
                float* elp = (t < 2) ? elm : elv;
                float* erp = (t < 2) ? erm : erv;
                elp[row * 2 + (t & 1)] = pe; erp[row * 2 + (t & 1)] = pr;
            }
            if (row < M) featmv[(size_t)row * 64 + t * 16 + m] = f2bf(a);
        }
    }
}

// ---------------- aggregation: layer 1 (H=1,F=128), 2 nodes/wave, single-pass softmax ----------------
__global__ __launch_bounds__(256) void k_agg1(const int* __restrict__ row_ptr, const int* __restrict__ esrc,
                                              const u16* __restrict__ feat, const float* __restrict__ el,
                                              const float* __restrict__ er, const float* __restrict__ bias,
                                              const float* __restrict__ ul, const float* __restrict__ ur,
                                              u16* __restrict__ o_bf, float* __restrict__ el2,
                                              float* __restrict__ er2, int n) {
    int wave = threadIdx.x >> 6, lane = threadIdx.x & 63;
    int l = lane & 31;
    int node = blockIdx.x * 8 + wave * 2 + (lane >> 5);
    if (node >= n) node = n - 1;               // N%8==0: never taken, keeps shfl convergent
    int beg = row_ptr[node], deg = row_ptr[node + 1] - beg;
    float erd = er[node];
    int degmax = max(deg, __shfl_xor(deg, 32));
    const int srcb = lane & 32;
    float acc0 = 0.f, acc1 = 0.f, acc2 = 0.f, acc3 = 0.f, den = 0.f;
    for (int off0 = 0; off0 < degmax; off0 += 32) {
        float w = 0.f; int s = 0;
        if (off0 + l < deg) { s = esrc[beg + off0 + l]; w = expf(lrelu(el[s] + erd)); }
        den += w;
        int cnt = min(32, degmax - off0);
        int j = 0;
        for (; j + 4 <= cnt; j += 4) {
            int s0 = __shfl(s, srcb + j),     s1 = __shfl(s, srcb + j + 1);
            int s2 = __shfl(s, srcb + j + 2), s3 = __shfl(s, srcb + j + 3);
            float w0 = __shfl(w, srcb + j),     w1 = __shfl(w, srcb + j + 1);
            float w2 = __shfl(w, srcb + j + 2), w3 = __shfl(w, srcb + j + 3);
            u32x2 p0 = ((const u32x2*)(feat + (size_t)s0 * 128))[l];
            u32x2 p1 = ((const u32x2*)(feat + (size_t)s1 * 128))[l];
            u32x2 p2 = ((const u32x2*)(feat + (size_t)s2 * 128))[l];
            u32x2 p3 = ((const u32x2*)(feat + (size_t)s3 * 128))[l];
            acc0 += w0 * bf2f((u16)(p0.x & 0xffff)) + w1 * bf2f((u16)(p1.x & 0xffff))
                  + w2 * bf2f((u16)(p2.x & 0xffff)) + w3 * bf2f((u16)(p3.x & 0xffff));
            acc1 += w0 * bf2f((u16)(p0.x >> 16)) + w1 * bf2f((u16)(p1.x >> 16))
                  + w2 * bf2f((u16)(p2.x >> 16)) + w3 * bf2f((u16)(p3.x >> 16));
            acc2 += w0 * bf2f((u16)(p0.y & 0xffff)) + w1 * bf2f((u16)(p1.y & 0xffff))
                  + w2 * bf2f((u16)(p2.y & 0xffff)) + w3 * bf2f((u16)(p3.y & 0xffff));
            acc3 += w0 * bf2f((u16)(p0.y >> 16)) + w1 * bf2f((u16)(p1.y >> 16))
                  + w2 * bf2f((u16)(p2.y >> 16)) + w3 * bf2f((u16)(p3.y >> 16));
        }
        for (; j < cnt; ++j) {
            int sj = __shfl(s, srcb + j);
            float wj = __shfl(w, srcb + j);
            u32x2 pv = ((const u32x2*)(feat + (size_t)sj * 128))[l];
            acc0 += wj * bf2f((u16)(pv.x & 0xffff));
            acc1 += wj * bf2f((u16)(pv.x >> 16));
            acc2 += wj * bf2f((u16)(pv.y & 0xffff));
            acc3 += wj * bf2f((u16)(pv.y >> 16));
        }
    }
#pragma unroll
    for (int off = 16; off; off >>= 1) den += __shfl_xor(den, off);
    float inv = (den > 0.f) ? 1.f / den : 0.f;
    const int c0 = 4 * l;
    float o0 = acc0 * inv + bias[c0];
    float o1 = acc1 * inv + bias[c0 + 1];
    float o2 = acc2 * inv + bias[c0 + 2];
    float o3 = acc3 * inv + bias[c0 + 3];
    // fused layer-2 attention logits from f32 o
#pragma unroll
    for (int h = 0; h < 2; ++h) {
        const float* ulh = ul + h * 128 + c0;
        const float* urh = ur + h * 128 + c0;
        float pe = o0 * ulh[0] + o1 * ulh[1] + o2 * ulh[2] + o3 * ulh[3];
        float pr = o0 * urh[0] + o1 * urh[1] + o2 * urh[2] + o3 * urh[3];
#pragma unroll
        for (int off = 16; off; off >>= 1) { pe += __shfl_xor(pe, off); pr += __shfl_xor(pr, off); }
        if (l == 0) { el2[node * 2 + h] = pe; er2[node * 2 + h] = pr; }
    }
    u32x2 pv;
    pv.x = (u32)f2bf(o0) | ((u32)f2bf(o1) << 16);
    pv.y = (u32)f2bf(o2) | ((u32)f2bf(o3) << 16);
    ((u32x2*)(o_bf + (size_t)node * 128))[l] = pv;
}

// ---------------- aggregation layer 2 over o (H=2 weights, 128-dim payload), 2 nodes/wave, 4-wide ----------------
__global__ __launch_bounds__(256) void k_agg2o(const int* __restrict__ row_ptr, const int* __restrict__ esrc,
                                               const u16* __restrict__ o_in, const float* __restrict__ el,
                                               const float* __restrict__ er, u16* __restrict__ agg, int n) {
    int wave = threadIdx.x >> 6, lane = threadIdx.x & 63;
    int l = lane & 31;
    int node = blockIdx.x * 8 + wave * 2 + (lane >> 5);
    if (node >= n) node = n - 1;
    int beg = row_ptr[node], deg = row_ptr[node + 1] - beg;
    float er0 = er[node * 2], er1 = er[node * 2 + 1];
    int degmax = max(deg, __shfl_xor(deg, 32));
    const int srcb = lane & 32;
    float a00 = 0.f, a01 = 0.f, a02 = 0.f, a03 = 0.f;
    float a10 = 0.f, a11 = 0.f, a12 = 0.f, a13 = 0.f;
    float d0 = 0.f, d1 = 0.f;
    for (int off0 = 0; off0 < degmax; off0 += 32) {
        float w0 = 0.f, w1 = 0.f; int s = 0;
        if (off0 + l < deg) {
            s = esrc[beg + off0 + l];
            float2 e2 = *(const float2*)(el + 2 * s);
            w0 = expf(lrelu(e2.x + er0));
            w1 = expf(lrelu(e2.y + er1));
        }
        d0 += w0; d1 += w1;
        int cnt = min(32, degmax - off0);
        int j = 0;
        for (; j + 4 <= cnt; j += 4) {
            int sa = __shfl(s, srcb + j),     sb = __shfl(s, srcb + j + 1);
            int sc = __shfl(s, srcb + j + 2), sd = __shfl(s, srcb + j + 3);
            float w0a = __shfl(w0, srcb + j),     w0b = __shfl(w0, srcb + j + 1);
            float w0c = __shfl(w0, srcb + j + 2), w0d = __shfl(w0, srcb + j + 3);
            float w1a = __shfl(w1, srcb + j),     w1b = __shfl(w1, srcb + j + 1);
            float w1c = __shfl(w1, srcb + j + 2), w1d = __shfl(w1, srcb + j + 3);
            u32x2 pa = ((const u32x2*)(o_in + (size_t)sa * 128))[l];
            u32x2 pb = ((const u32x2*)(o_in + (size_t)sb * 128))[l];
            u32x2 pc = ((const u32x2*)(o_in + (size_t)sc * 128))[l];
            u32x2 pd = ((const u32x2*)(o_in + (size_t)sd * 128))[l];
            float fa0 = bf2f((u16)(pa.x & 0xffff)), fa1 = bf2f((u16)(pa.x >> 16));
            float fa2 = bf2f((u16)(pa.y & 0xffff)), fa3 = bf2f((u16)(pa.y >> 16));
            float fb0 = bf2f((u16)(pb.x & 0xffff)), fb1 = bf2f((u16)(pb.x >> 16));
            float fb2 = bf2f((u16)(pb.y & 0xffff)), fb3 = bf2f((u16)(pb.y >> 16));
            float fc0 = bf2f((u16)(pc.x & 0xffff)), fc1 = bf2f((u16)(pc.x >> 16));
            float fc2 = bf2f((u16)(pc.y & 0xffff)), fc3 = bf2f((u16)(pc.y >> 16));
            float fd0 = bf2f((u16)(pd.x & 0xffff)), fd1 = bf2f((u16)(pd.x >> 16));
            float fd2 = bf2f((u16)(pd.y & 0xffff)), fd3 = bf2f((u16)(pd.y >> 16));
            a00 += w0a * fa0 + w0b * fb0 + w0c * fc0 + w0d * fd0;
            a01 += w0a * fa1 + w0b * fb1 + w0c * fc1 + w0d * fd1;
            a02 += w0a * fa2 + w0b * fb2 + w0c * fc2 + w0d * fd2;
            a03 += w0a * fa3 + w0b * fb3 + w0c * fc3 + w0d * fd3;
            a10 += w1a * fa0 + w1b * fb0 + w1c * fc0 + w1d * fd0;
            a11 += w1a * fa1 + w1b * fb1 + w1c * fc1 + w1d * fd1;
            a12 += w1a * fa2 + w1b * fb2 + w1c * fc2 + w1d * fd2;
            a13 += w1a * fa3 + w1b * fb3 + w1c * fc3 + w1d * fd3;
        }
        for (; j < cnt; ++j) {
            int sj = __shfl(s, srcb + j);
            float w0j = __shfl(w0, srcb + j), w1j = __shfl(w1, srcb + j);
            u32x2 pv = ((const u32x2*)(o_in + (size_t)sj * 128))[l];
            float f0 = bf2f((u16)(pv.x & 0xffff)), f1 = bf2f((u16)(pv.x >> 16));
            float f2 = bf2f((u16)(pv.y & 0xffff)), f3 = bf2f((u16)(pv.y >> 16));
            a00 += w0j * f0; a01 += w0j * f1; a02 += w0j * f2; a03 += w0j * f3;
            a10 += w1j * f0; a11 += w1j * f1; a12 += w1j * f2; a13 += w1j * f3;
        }
    }
#pragma unroll
    for (int off = 16; off; off >>= 1) { d0 += __shfl_xor(d0, off); d1 += __shfl_xor(d1, off); }
    float i0 = (d0 > 0.f) ? 1.f / d0 : 0.f, i1 = (d1 > 0.f) ? 1.f / d1 : 0.f;
    u32x2 p0, p1;
    p0.x = (u32)f2bf(a00 * i0) | ((u32)f2bf(a01 * i0) << 16);
    p0.y = (u32)f2bf(a02 * i0) | ((u32)f2bf(a03 * i0) << 16);
    p1.x = (u32)f2bf(a10 * i1) | ((u32)f2bf(a11 * i1) << 16);
    p1.y = (u32)f2bf(a12 * i1) | ((u32)f2bf(a13 * i1) << 16);
    u32x2* aw = (u32x2*)(agg + (size_t)node * 256);
    aw[l] = p0;           // head0 -> cols 0..127
    aw[32 + l] = p1;      // head1 -> cols 128..255
}

// ---------------- mean & var aggregation (interleaved featmv [N,64]), 2 nodes/wave + reparam ----------------
// Weight distribution via per-wave LDS staging (replaces 4 shfl + select per edge with one
// broadcast ds_read selected by wtype = l>>3). Producer/consumer are the same wave: no barrier.
__global__ __launch_bounds__(256) void k_aggmv(const int* __restrict__ row_ptr, const int* __restrict__ esrc,
                                               const u16* __restrict__ featmv,
                                               const float* __restrict__ elm, const float* __restrict__ erm,
                                               const float* __restrict__ elv, const float* __restrict__ erv,
                                               const float* __restrict__ bm, const float* __restrict__ bv,
                                               const float* __restrict__ eps, float* __restrict__ out, int n) {
    __shared__ float wsm[256 * 4];
    __shared__ int ssm[256];
    int tid = threadIdx.x;
    int wave = tid >> 6, lane = tid & 63;
    int l = lane & 31;
    int node = blockIdx.x * 8 + wave * 2 + (lane >> 5);
    if (node >= n) node = n - 1;
    int tbl = l >> 4, h = (l >> 3) & 1;
    const int wtype = l >> 3;                     // 0..3 = m-h0, m-h1, v-h0, v-h1
    int beg = row_ptr[node], deg = row_ptr[node + 1] - beg;
    float erm0 = erm[2 * node], erm1 = erm[2 * node + 1];
    float erv0 = erv[2 * node], erv1 = erv[2 * node + 1];
    int degmax = max(deg, __shfl_xor(deg, 32));
    const int bidx = wave * 64 + (lane & 32);     // broadcaster base thread idx for this half
    float acc0 = 0.f, acc1 = 0.f;
    float dm0 = 0.f, dm1 = 0.f, dv0 = 0.f, dv1 = 0.f;
    for (int off0 = 0; off0 < degmax; off0 += 32) {
        float wm0 = 0.f, wm1 = 0.f, wv0 = 0.f, wv1 = 0.f; int s = 0;
        if (off0 + l < deg) {
            s = esrc[beg + off0 + l];
            float2 em = *(const float2*)(elm + 2 * s);
            float2 ev = *(const float2*)(elv + 2 * s);
            wm0 = expf(lrelu(em.x + erm0));
            wm1 = expf(lrelu(em.y + erm1));
            wv0 = expf(lrelu(ev.x + erv0));
            wv1 = expf(lrelu(ev.y + erv1));
        }
        dm0 += wm0; dm1 += wm1; dv0 += wv0; dv1 += wv1;
        f32x4 wq; wq[0] = wm0; wq[1] = wm1; wq[2] = wv0; wq[3] = wv1;
        *(f32x4*)&wsm[tid * 4] = wq;
        ssm[tid] = s;
        int cnt = min(32, degmax - off0);
        int j = 0;
        for (; j + 2 <= cnt; j += 2) {
            int sa = ssm[bidx + j], sb = ssm[bidx + j + 1];
            float wa = wsm[(bidx + j) * 4 + wtype];
            float wb = wsm[(bidx + j + 1) * 4 + wtype];
            u32 pa = ((const u32*)(featmv + (size_t)sa * 64))[l];
            u32 pb = ((const u32*)(featmv + (size_t)sb * 64))[l];
            acc0 += wa * bf2f((u16)(pa & 0xffff)) + wb * bf2f((u16)(pb & 0xffff));
            acc1 += wa * bf2f((u16)(pa >> 16)) + wb * bf2f((u16)(pb >> 16));
        }
        for (; j < cnt; ++j) {
            int sj = ssm[bidx + j];
            float wj = wsm[(bidx + j) * 4 + wtype];
            u32 pv = ((const u32*)(featmv + (size_t)sj * 64))[l];
            acc0 += wj * bf2f((u16)(pv & 0xffff));
            acc1 += wj * bf2f((u16)(pv >> 16));
        }
    }
#pragma unroll
    for (int off = 16; off; off >>= 1) {
        dm0 += __shfl_xor(dm0, off); dm1 += __shfl_xor(dm1, off);
        dv0 += __shfl_xor(dv0, off); dv1 += __shfl_xor(dv1, off);
    }
    float den = tbl ? (h ? dv1 : dv0) : (h ? dm1 : dm0);
    float inv = (den > 0.f) ? 1.f / den : 0.f;
    const int fidx0 = (2 * l) & 31;                 // table-local col (h*16 + f)
    float bias0 = tbl ? bv[fidx0] : bm[fidx0];
    float bias1 = tbl ? bv[fidx0 + 1] : bm[fidx0 + 1];
    float outc0 = acc0 * inv + bias0;
    float outc1 = acc1 * inv + bias1;
    // head-mean: lanes l and l^8 hold the same (tbl, f) pair for the two heads
    float hm0 = 0.5f * (outc0 + __shfl_xor(outc0, 8));
    float hm1 = 0.5f * (outc1 + __shfl_xor(outc1, 8));
    // var projections live on tbl=1 lanes (16..23 within half)
    int srcv = (lane & 32) + 16 + (l & 7);
    float vp0 = __shfl(hm0, srcv);
    float vp1 = __shfl(hm1, srcv);
    if (l < 8) {
        int f0 = 2 * l;
        float var0 = expf(vp0), var1 = expf(vp1);
        float2 e2 = *(const float2*)(eps + (size_t)node * 16 + f0);
        float z0 = hm0 + sqrtf(var0) * e2.x;
        float z1 = hm1 + sqrtf(var1) * e2.y;
        size_t base = (size_t)node * 16 + f0;
        *(float2*)(out + base) = make_float2(z0, z1);
        *(float2*)(out + (size_t)NNODES * 16 + base) = make_float2(hm0, hm1);
        *(float2*)(out + (size_t)2 * NNODES * 16 + base) = make_float2(var0, var1);
    }
}

// ---------------- host ----------------
extern "C" void kernel_launch(void* const* d_in, const int* in_sizes, int n_in,
                              void* d_out, int out_size, void* d_ws, size_t ws_size,
                              hipStream_t stream) {
    const int N = NNODES, E = NEDGES;
    const float* x   = (const float*)d_in[0];
    const int* src   = (const int*)d_in[1];
    const int* dst   = (const int*)d_in[2];
    const float* W1  = (const float*)d_in[3];
    const float* al1 = (const float*)d_in[4];
    const float* ar1 = (const float*)d_in[5];
    const float* b1  = (const float*)d_in[6];
    const float* W2  = (const float*)d_in[7];
    const float* al2 = (const float*)d_in[8];
    const float* ar2 = (const float*)d_in[9];
    const float* b2  = (const float*)d_in[10];
    const float* Wm  = (const float*)d_in[11];
    const float* alm = (const float*)d_in[12];
    const float* arm = (const float*)d_in[13];
    const float* bm  = (const float*)d_in[14];
    const float* Wv  = (const float*)d_in[15];
    const float* alv = (const float*)d_in[16];
    const float* arv = (const float*)d_in[17];
    const float* bv  = (const float*)d_in[18];
    const float* eps = (const float*)d_in[19];
    float* out = (float*)d_out;

    char* ws = (char*)d_ws;
    size_t off = 0;
    auto take = [&](size_t bytes) { size_t r = off; off += (bytes + 255) & ~(size_t)255; return r; };
    int* counts   = (int*)(ws + take((size_t)N * 4));
    int* cursor   = (int*)(ws + take((size_t)N * 4));
    int* row_ptr  = (int*)(ws + take((size_t)(N + 1) * 4));
    int* bsums    = (int*)(ws + take(256 * 4));
    int* esrc     = (int*)(ws + take((size_t)E * 4));
    u16* W1t      = (u16*)(ws + take((size_t)128 * 1000 * 2));
    u16* Wct      = (u16*)(ws + take((size_t)128 * 256 * 2));
    u16* Bmvt     = (u16*)(ws + take((size_t)64 * 128 * 2));
    float* ul2    = (float*)(ws + take(256 * 4));
    float* ur2    = (float*)(ws + take(256 * 4));
    float* bmean  = (float*)(ws + take(128 * 4));
    float* el1    = (float*)(ws + take((size_t)N * 4));
    float* er1    = (float*)(ws + take((size_t)N * 4));
    float* el2    = (float*)(ws + take((size_t)N * 2 * 4));
    float* er2    = (float*)(ws + take((size_t)N * 2 * 4));
    float* elm    = (float*)(ws + take((size_t)N * 2 * 4));
    float* erm    = (float*)(ws + take((size_t)N * 2 * 4));
    float* elv    = (float*)(ws + take((size_t)N * 2 * 4));
    float* erv    = (float*)(ws + take((size_t)N * 2 * 4));
    u16* o_bf     = (u16*)(ws + take((size_t)N * 128 * 2));
    u16* o2_bf    = (u16*)(ws + take((size_t)N * 128 * 2));
    u16* R        = (u16*)(ws + take((size_t)N * 256 * 2));
    u16* feat1    = R;          // layer-1 features [N,128]
    u16* agg      = R;          // layer-2 weighted aggregation of o [N,256] (after feat1 consumed)
    u16* featmv   = R;          // interleaved mv features [N,64] (after agg consumed)
    (void)ws_size; (void)n_in; (void)in_sizes; (void)out_size;

    const int nb = (N + 255) / 256;
    const int eb = (E + 255) / 256;
    const int wb8 = (N + 7) / 8;
    const int gb = (N + 63) / 64;

    // fused weight prep (independent of CSR)
    k_prep<<<dim3(630), 256, 0, stream>>>(W1, W2, Wm, Wv, al2, ar2, b2, W1t, Wct, Bmvt, ul2, ur2, bmean);

    // CSR build
    k_zero2<<<dim3(nb), 256, 0, stream>>>(counts, cursor, N);
    k_count<<<dim3(eb), 256, 0, stream>>>(dst, counts, E);
    k_scan1<<<dim3(nb), 256, 0, stream>>>(counts, row_ptr, bsums, N);
    k_scan2<<<dim3(1), 256, 0, stream>>>(bsums, nb);
    k_scan3<<<dim3(nb), 256, 0, stream>>>(row_ptr, bsums, N, E);
    k_fill<<<dim3(eb), 256, 0, stream>>>(src, dst, row_ptr, cursor, esrc, E);

    // layer 1 (A is f32): K-chunked GEMM + fused el1/er1
    k_gemm_tiled<float, 0><<<dim3(gb), 256, 0, stream>>>(x, W1t, feat1, N, 128, 1000,
                                                         nullptr, nullptr, al1, ar1, el1, er1);
    k_agg1<<<dim3(wb8), 256, 0, stream>>>(row_ptr, esrc, feat1, el1, er1, b1, ul2, ur2,
                                          o_bf, el2, er2, N);

    // layer 2: aggregate o; project+bias+residual in GEMM epilogue (single K-chunk)
    k_agg2o<<<dim3(wb8), 256, 0, stream>>>(row_ptr, esrc, o_bf, el2, er2, agg, N);
    k_gemm_tiled<u16, 1><<<dim3(gb), 256, 0, stream>>>(agg, Wct, o2_bf, N, 128, 256,
                                                       bmean, o_bf, nullptr, nullptr, nullptr, nullptr);

    // mean/var: single fused GEMM (m|v) + fused logits
    k_gemmmv<<<dim3(N / 16), 64, 0, stream>>>(o2_bf, Bmvt, featmv, alm, arm, alv, arv,
                                              elm, erm, elv, erv, N);
    k_aggmv<<<dim3(wb8), 256, 0, stream>>>(row_ptr, esrc, featmv, elm, erm, elv, erv,
                                           bm, bv, eps, out, N);
}

// Round 8
// 567.725 us; speedup vs baseline: 1.0201x; 1.0201x over previous
//
#include <hip/hip_runtime.h>
#include <hip/hip_bf16.h>
#include <math.h>

typedef unsigned short u16;
typedef unsigned int u32;
typedef __attribute__((ext_vector_type(8))) __bf16 bf16x8;
typedef __attribute__((ext_vector_type(4))) float f32x4;
typedef __attribute__((ext_vector_type(4))) u32 u32x4;
typedef __attribute__((ext_vector_type(2))) u32 u32x2;

#define NNODES 50000
#define NEDGES 800000

__device__ __forceinline__ float bf2f(u16 u) {
    union { u32 i; float f; } v; v.i = ((u32)u) << 16; return v.f;
}
__device__ __forceinline__ u16 f2bf(float x) {
    union { float f; u32 i; } v; v.f = x;
    u32 r = v.i + 0x7fffu + ((v.i >> 16) & 1u);
    return (u16)(r >> 16);
}
__device__ __forceinline__ float lrelu(float x) { return x >= 0.f ? x : 0.2f * x; }

// async global->LDS 16B (direct DMA, no VGPR round trip)
__device__ __forceinline__ void gload_lds16(const u16* g, u16* l) {
    __builtin_amdgcn_global_load_lds((const __attribute__((address_space(1))) u32*)g,
                                     (__attribute__((address_space(3))) u32*)l, 16, 0, 0);
}

// ---------------- CSR build ----------------
__global__ __launch_bounds__(256) void k_zero2(int* a, int* b, int count) {
    int i = blockIdx.x * 256 + threadIdx.x;
    if (i < count) { a[i] = 0; b[i] = 0; }
}

__global__ __launch_bounds__(256) void k_count(const int* __restrict__ dst, int* __restrict__ counts, int e) {
    int i = blockIdx.x * 256 + threadIdx.x;
    if (i < e) atomicAdd(&counts[dst[i]], 1);
}

__global__ __launch_bounds__(256) void k_scan1(const int* __restrict__ counts, int* __restrict__ row_ptr,
                                               int* __restrict__ bsums, int n) {
    __shared__ int tmp[256];
    int t = threadIdx.x, i = blockIdx.x * 256 + t;
    int v = (i < n) ? counts[i] : 0;
    tmp[t] = v; __syncthreads();
    for (int off = 1; off < 256; off <<= 1) {
        int x = 0; if (t >= off) x = tmp[t - off];
        __syncthreads(); tmp[t] += x; __syncthreads();
    }
    if (i < n) row_ptr[i] = tmp[t] - v;
    if (t == 255) bsums[blockIdx.x] = tmp[255];
}

__global__ __launch_bounds__(256) void k_scan2(int* bsums, int nb) {
    __shared__ int tmp[256];
    int t = threadIdx.x;
    int v = (t < nb) ? bsums[t] : 0;
    tmp[t] = v; __syncthreads();
    for (int off = 1; off < 256; off <<= 1) {
        int x = 0; if (t >= off) x = tmp[t - off];
        __syncthreads(); tmp[t] += x; __syncthreads();
    }
    if (t < nb) bsums[t] = tmp[t] - v;
}

__global__ __launch_bounds__(256) void k_scan3(int* __restrict__ row_ptr, const int* __restrict__ bsums,
                                               int n, int total) {
    int i = blockIdx.x * 256 + threadIdx.x;
    if (i < n) row_ptr[i] += bsums[blockIdx.x];
    if (i == 0) row_ptr[n] = total;
}

__global__ __launch_bounds__(256) void k_fill(const int* __restrict__ src, const int* __restrict__ dst,
                                              const int* __restrict__ row_ptr, int* __restrict__ cursor,
                                              int* __restrict__ esrc, int e) {
    int i = blockIdx.x * 256 + threadIdx.x;
    if (i < e) {
        int d = dst[i];
        int p = row_ptr[d] + atomicAdd(&cursor[d], 1);
        esrc[p] = src[i];
    }
}

// ---------------- fused weight prep ----------------
__global__ __launch_bounds__(256) void k_prep(const float* __restrict__ W1, const float* __restrict__ W2,
                                              const float* __restrict__ Wm, const float* __restrict__ Wv,
                                              const float* __restrict__ al2, const float* __restrict__ ar2,
                                              const float* __restrict__ b2,
                                              u16* __restrict__ W1t, u16* __restrict__ Wct,
                                              u16* __restrict__ Bmvt,
                                              float* __restrict__ ul, float* __restrict__ ur,
                                              float* __restrict__ bmean) {
    int b = blockIdx.x, t = threadIdx.x;
    if (b < 500) {
        int i = b * 256 + t;           // i < 128000
        int k = i >> 7, n = i & 127;
        W1t[(size_t)n * 1000 + k] = f2bf(W1[i]);
    } else if (b < 628) {
        int i = (b - 500) * 256 + t;   // i < 32768
        int f = i >> 8, c = i & 255, h = c >> 7, k = c & 127;
        Wct[i] = f2bf(0.5f * W2[(size_t)k * 256 + h * 128 + f]);
    } else if (b == 628) {
        int h = t >> 7, k = t & 127;
        const float* wrow = W2 + (size_t)k * 256 + h * 128;
        const float* alh = al2 + h * 128;
        const float* arh = ar2 + h * 128;
        float sl = 0.f, sr = 0.f;
        for (int f = 0; f < 128; f += 4) {
            f32x4 w = *(const f32x4*)(wrow + f);
            f32x4 a = *(const f32x4*)(alh + f);
            f32x4 r = *(const f32x4*)(arh + f);
#pragma unroll
            for (int q = 0; q < 4; q++) { sl += w[q] * a[q]; sr += w[q] * r[q]; }
        }
        ul[t] = sl; ur[t] = sr;
        if (t < 128) bmean[t] = 0.5f * (b2[t] + b2[128 + t]);
    } else {
        for (int i = t; i < 64 * 128; i += 256) {
            int c = i >> 7, k = i & 127;
            Bmvt[i] = f2bf(c < 32 ? Wm[(size_t)k * 32 + c] : Wv[(size_t)k * 32 + (c - 32)]);
        }
    }
}

// ---------------- K-chunked MFMA GEMM with COALESCED A-staging ----------------
// C[M,128](bf16) = A[M,K] * Bt[128,K]^T.
// Per-lane-row A loads (64-lane scatter) capped the old kernel at ~950 GB/s effective
// (122us invariant across barrier structures). Here the block cooperatively stages each
// 128-wide K-chunk of A with fully COALESCED reads (consecutive lanes -> consecutive 16B
// of the SAME row), f32->bf16 in regs, ds_write to padded LDS [64][136] (row pitch 272B).
// B keeps the conflict-free [granule][col][8] global_load_lds layout. A-loads for chunk
// c+1 issue BEFORE chunk c's MFMAs so HBM latency hides under compute. LDS 49KB.
// ROUND-7 FIX: fragment read row is (wave*16 + m), not m — the block-shared A tile needs
// the wave's row offset (missing offset made all 4 waves read wave-0 rows, absmax 0.56).
// K-tail: OOB A segments are zero-filled; stale B granules then contribute exactly 0.
// MODE 0: layer-1 — also emit el/er attention projections from f32 accumulators.
// MODE 1: layer-2 — C = f2bf(acc + bias[col] + bf2f(resid[row*128+col]))
template <typename AT, int MODE>
__global__ __launch_bounds__(256) void k_gemm_tiled(const AT* __restrict__ A, const u16* __restrict__ Bt,
                                                    u16* __restrict__ C, int M, int Nn, int K,
                                                    const float* __restrict__ bias,
                                                    const u16* __restrict__ resid,
                                                    const float* __restrict__ al,
                                                    const float* __restrict__ ar,
                                                    float* __restrict__ el, float* __restrict__ er) {
    __shared__ __align__(16) u16 Alds[64 * 136];      // 17 KB (+8 u16 row pad)
    __shared__ __align__(16) u16 Blds[16 * 128 * 8];  // 32 KB [granule<16][col<128][8]
    const int tid = threadIdx.x;
    const int wave = tid >> 6, lane = tid & 63;
    const int m = lane & 15, quad = lane >> 4;
    const int row0b = blockIdx.x * 64;                // block row base (A staging)
    const int row0 = row0b + wave * 16;               // wave row base (output)

    f32x4 acc[8];
#pragma unroll
    for (int t = 0; t < 8; t++)
#pragma unroll
        for (int r = 0; r < 4; r++) acc[t][r] = 0.f;

    const int scol = tid & 127, shi = tid >> 7;       // B staging: col + granule-half (wave-uniform)
    const u16* bcol = Bt + (size_t)scol * K;

    const int KC = 128;
    const int nchunks = (K + KC - 1) / KC;

    f32x4 aregf[8];   // f32 path: 8 units of f32x4  (row=u>>5, seg=u&31)
    u32x4 aregh[4];   // bf16 path: 4 units of 8xu16 (row=u>>4, seg=u&15)

    auto issueA = [&](int kb) {
        if constexpr (sizeof(AT) == 4) {
#pragma unroll
            for (int i = 0; i < 8; ++i) {
                int u = i * 256 + tid;
                int rw = u >> 5, sg = u & 31;
                int arr = row0b + rw; if (arr > M - 1) arr = M - 1;
                int k0 = kb + sg * 4;
                f32x4 v = {0.f, 0.f, 0.f, 0.f};
                if (k0 + 4 <= K) v = *(const f32x4*)((const float*)A + (size_t)arr * K + k0);
                aregf[i] = v;
            }
        } else {
#pragma unroll
            for (int i = 0; i < 4; ++i) {
                int u = i * 256 + tid;
                int rw = u >> 4, sg = u & 15;
                int arr = row0b + rw; if (arr > M - 1) arr = M - 1;
                int k0 = kb + sg * 8;
                u32x4 v = {0, 0, 0, 0};
                if (k0 + 8 <= K) v = *(const u32x4*)((const u16*)A + (size_t)arr * K + k0);
                aregh[i] = v;
            }
        }
    };
    auto writeA = [&]() {
        if constexpr (sizeof(AT) == 4) {
#pragma unroll
            for (int i = 0; i < 8; ++i) {
                int u = i * 256 + tid;
                int rw = u >> 5, sg = u & 31;
                u32x2 pk;
                pk.x = ((u32)f2bf(aregf[i][1]) << 16) | f2bf(aregf[i][0]);
                pk.y = ((u32)f2bf(aregf[i][3]) << 16) | f2bf(aregf[i][2]);
                *(u32x2*)&Alds[rw * 136 + sg * 4] = pk;
            }
        } else {
#pragma unroll
            for (int i = 0; i < 4; ++i) {
                int u = i * 256 + tid;
                int rw = u >> 4, sg = u & 15;
                *(u32x4*)&Alds[rw * 136 + sg * 8] = aregh[i];
            }
        }
    };
    auto stageB = [&](int kb) {
#pragma unroll
        for (int it = 0; it < 8; ++it) {
            int g = it * 2 + shi;
            int kq = kb + g * 8;
            if (kq < K) gload_lds16(bcol + kq, &Blds[((size_t)g * 128 + scol) * 8]);
        }
    };

    // prologue: chunk 0 fully staged
    issueA(0);
    writeA();
    stageB(0);
    __syncthreads();

    for (int c = 0; c < nchunks; ++c) {
        const int kbn = (c + 1) * KC;
        if (c + 1 < nchunks) issueA(kbn);    // HBM latency hides under MFMAs below
#pragma unroll
        for (int ks = 0; ks < 4; ++ks) {
            bf16x8 a = *(const bf16x8*)&Alds[(wave * 16 + m) * 136 + ks * 32 + quad * 8];
#pragma unroll
            for (int t = 0; t < 8; ++t) {
                bf16x8 b = *(const bf16x8*)&Blds[((ks * 4 + quad) * 128 + t * 16 + m) * 8];
                acc[t] = __builtin_amdgcn_mfma_f32_16x16x32_bf16(a, b, acc[t], 0, 0, 0);
            }
        }
        __syncthreads();                     // all waves done reading chunk c
        if (c + 1 < nchunks) {
            writeA();
            stageB(kbn);
        }
        __syncthreads();                     // chunk c+1 resident
    }

#pragma unroll
    for (int r = 0; r < 4; r++) {
        int row = row0 + quad * 4 + r;
        if (MODE == 0) {
            float pe = 0.f, pr = 0.f;
#pragma unroll
            for (int t = 0; t < 8; t++) {
                float a = acc[t][r];
                int c = t * 16 + m;
                pe += a * al[c]; pr += a * ar[c];
            }
#pragma unroll
            for (int off = 8; off; off >>= 1) { pe += __shfl_xor(pe, off); pr += __shfl_xor(pr, off); }
            if (m == 0 && row < M) { el[row] = pe; er[row] = pr; }
        }
#pragma unroll
        for (int t = 0; t < 8; t++) {
            int col = t * 16 + m;
            if (row < M) {
                float v = acc[t][r];
                if (MODE == 1) v += bias[col] + bf2f(resid[(size_t)row * Nn + col]);
                C[(size_t)row * Nn + col] = f2bf(v);
            }
        }
    }
}

// ---------------- fused mean/var GEMM: [N,128] x [128,64] ([Wm|Wv] combined) ----------------
__global__ __launch_bounds__(64) void k_gemmmv(const u16* __restrict__ A, const u16* __restrict__ Bt,
                                               u16* __restrict__ featmv,
                                               const float* __restrict__ alm, const float* __restrict__ arm,
                                               const float* __restrict__ alv, const float* __restrict__ arv,
                                               float* __restrict__ elm, float* __restrict__ erm,
                                               float* __restrict__ elv, float* __restrict__ erv, int M) {
    int row0 = blockIdx.x * 16;
    int lane = threadIdx.x;
    int m = lane & 15, quad = lane >> 4;
    f32x4 acc[4];
#pragma unroll
    for (int t = 0; t < 4; t++)
#pragma unroll
        for (int r = 0; r < 4; r++) acc[t][r] = 0.f;

    const u16* arow = A + (size_t)(row0 + m) * 128 + quad * 8;
#pragma unroll
    for (int s = 0; s < 4; ++s) {
        bf16x8 a = *(const bf16x8*)(arow + s * 32);
#pragma unroll
        for (int t = 0; t < 4; t++) {
            bf16x8 b = *(const bf16x8*)(Bt + (size_t)(t * 16 + m) * 128 + s * 32 + quad * 8);
            acc[t] = __builtin_amdgcn_mfma_f32_16x16x32_bf16(a, b, acc[t], 0, 0, 0);
        }
    }
#pragma unroll
    for (int r = 0; r < 4; r++) {
        int row = row0 + quad * 4 + r;
#pragma unroll
        for (int t = 0; t < 4; t++) {
            float a = acc[t][r];
            const float* alp = (t < 2) ? alm : alv;
            const float* arp = (t < 2) ? arm : arv;
            float pe = a * alp[(t & 1) * 16 + m];
            float pr = a * arp[(t & 1) * 16 + m];
#pragma unroll
            for (int off = 8; off; off >>= 1) { pe += __shfl_xor(pe, off); pr += __shfl_xor(pr, off); }
            if (m == 0 && row < M) {
                float* elp = (t < 2) ? elm : elv;
                float* erp = (t < 2) ? erm : erv;
                elp[row * 2 + (t & 1)] = pe; erp[row * 2 + (t & 1)] = pr;
            }
            if (row < M) featmv[(size_t)row * 64 + t * 16 + m] = f2bf(a);
        }
    }
}

// ---------------- aggregation: layer 1 (H=1,F=128), 2 nodes/wave, single-pass softmax ----------------
__global__ __launch_bounds__(256) void k_agg1(const int* __restrict__ row_ptr, const int* __restrict__ esrc,
                                              const u16* __restrict__ feat, const float* __restrict__ el,
                                              const float* __restrict__ er, const float* __restrict__ bias,
                                              const float* __restrict__ ul, const float* __restrict__ ur,
                                              u16* __restrict__ o_bf, float* __restrict__ el2,
                                              float* __restrict__ er2, int n) {
    int wave = threadIdx.x >> 6, lane = threadIdx.x & 63;
    int l = lane & 31;
    int node = blockIdx.x * 8 + wave * 2 + (lane >> 5);
    if (node >= n) node = n - 1;               // N%8==0: never taken, keeps shfl convergent
    int beg = row_ptr[node], deg = row_ptr[node + 1] - beg;
    float erd = er[node];
    int degmax = max(deg, __shfl_xor(deg, 32));
    const int srcb = lane & 32;
    float acc0 = 0.f, acc1 = 0.f, acc2 = 0.f, acc3 = 0.f, den = 0.f;
    for (int off0 = 0; off0 < degmax; off0 += 32) {
        float w = 0.f; int s = 0;
        if (off0 + l < deg) { s = esrc[beg + off0 + l]; w = expf(lrelu(el[s] + erd)); }
        den += w;
        int cnt = min(32, degmax - off0);
        int j = 0;
        for (; j + 4 <= cnt; j += 4) {
            int s0 = __shfl(s, srcb + j),     s1 = __shfl(s, srcb + j + 1);
            int s2 = __shfl(s, srcb + j + 2), s3 = __shfl(s, srcb + j + 3);
            float w0 = __shfl(w, srcb + j),     w1 = __shfl(w, srcb + j + 1);
            float w2 = __shfl(w, srcb + j + 2), w3 = __shfl(w, srcb + j + 3);
            u32x2 p0 = ((const u32x2*)(feat + (size_t)s0 * 128))[l];
            u32x2 p1 = ((const u32x2*)(feat + (size_t)s1 * 128))[l];
            u32x2 p2 = ((const u32x2*)(feat + (size_t)s2 * 128))[l];
            u32x2 p3 = ((const u32x2*)(feat + (size_t)s3 * 128))[l];
            acc0 += w0 * bf2f((u16)(p0.x & 0xffff)) + w1 * bf2f((u16)(p1.x & 0xffff))
                  + w2 * bf2f((u16)(p2.x & 0xffff)) + w3 * bf2f((u16)(p3.x & 0xffff));
            acc1 += w0 * bf2f((u16)(p0.x >> 16)) + w1 * bf2f((u16)(p1.x >> 16))
                  + w2 * bf2f((u16)(p2.x >> 16)) + w3 * bf2f((u16)(p3.x >> 16));
            acc2 += w0 * bf2f((u16)(p0.y & 0xffff)) + w1 * bf2f((u16)(p1.y & 0xffff))
                  + w2 * bf2f((u16)(p2.y & 0xffff)) + w3 * bf2f((u16)(p3.y & 0xffff));
            acc3 += w0 * bf2f((u16)(p0.y >> 16)) + w1 * bf2f((u16)(p1.y >> 16))
                  + w2 * bf2f((u16)(p2.y >> 16)) + w3 * bf2f((u16)(p3.y >> 16));
        }
        for (; j < cnt; ++j) {
            int sj = __shfl(s, srcb + j);
            float wj = __shfl(w, srcb + j);
            u32x2 pv = ((const u32x2*)(feat + (size_t)sj * 128))[l];
            acc0 += wj * bf2f((u16)(pv.x & 0xffff));
            acc1 += wj * bf2f((u16)(pv.x >> 16));
            acc2 += wj * bf2f((u16)(pv.y & 0xffff));
            acc3 += wj * bf2f((u16)(pv.y >> 16));
        }
    }
#pragma unroll
    for (int off = 16; off; off >>= 1) den += __shfl_xor(den, off);
    float inv = (den > 0.f) ? 1.f / den : 0.f;
    const int c0 = 4 * l;
    float o0 = acc0 * inv + bias[c0];
    float o1 = acc1 * inv + bias[c0 + 1];
    float o2 = acc2 * inv + bias[c0 + 2];
    float o3 = acc3 * inv + bias[c0 + 3];
    // fused layer-2 attention logits from f32 o
#pragma unroll
    for (int h = 0; h < 2; ++h) {
        const float* ulh = ul + h * 128 + c0;
        const float* urh = ur + h * 128 + c0;
        float pe = o0 * ulh[0] + o1 * ulh[1] + o2 * ulh[2] + o3 * ulh[3];
        float pr = o0 * urh[0] + o1 * urh[1] + o2 * urh[2] + o3 * urh[3];
#pragma unroll
        for (int off = 16; off; off >>= 1) { pe += __shfl_xor(pe, off); pr += __shfl_xor(pr, off); }
        if (l == 0) { el2[node * 2 + h] = pe; er2[node * 2 + h] = pr; }
    }
    u32x2 pv;
    pv.x = (u32)f2bf(o0) | ((u32)f2bf(o1) << 16);
    pv.y = (u32)f2bf(o2) | ((u32)f2bf(o3) << 16);
    ((u32x2*)(o_bf + (size_t)node * 128))[l] = pv;
}

// ---------------- aggregation layer 2 over o (H=2 weights, 128-dim payload), 2 nodes/wave, 4-wide ----------------
__global__ __launch_bounds__(256) void k_agg2o(const int* __restrict__ row_ptr, const int* __restrict__ esrc,
                                               const u16* __restrict__ o_in, const float* __restrict__ el,
                                               const float* __restrict__ er, u16* __restrict__ agg, int n) {
    int wave = threadIdx.x >> 6, lane = threadIdx.x & 63;
    int l = lane & 31;
    int node = blockIdx.x * 8 + wave * 2 + (lane >> 5);
    if (node >= n) node = n - 1;
    int beg = row_ptr[node], deg = row_ptr[node + 1] - beg;
    float er0 = er[node * 2], er1 = er[node * 2 + 1];
    int degmax = max(deg, __shfl_xor(deg, 32));
    const int srcb = lane & 32;
    float a00 = 0.f, a01 = 0.f, a02 = 0.f, a03 = 0.f;
    float a10 = 0.f, a11 = 0.f, a12 = 0.f, a13 = 0.f;
    float d0 = 0.f, d1 = 0.f;
    for (int off0 = 0; off0 < degmax; off0 += 32) {
        float w0 = 0.f, w1 = 0.f; int s = 0;
        if (off0 + l < deg) {
            s = esrc[beg + off0 + l];
            float2 e2 = *(const float2*)(el + 2 * s);
            w0 = expf(lrelu(e2.x + er0));
            w1 = expf(lrelu(e2.y + er1));
        }
        d0 += w0; d1 += w1;
        int cnt = min(32, degmax - off0);
        int j = 0;
        for (; j + 4 <= cnt; j += 4) {
            int sa = __shfl(s, srcb + j),     sb = __shfl(s, srcb + j + 1);
            int sc = __shfl(s, srcb + j + 2), sd = __shfl(s, srcb + j + 3);
            float w0a = __shfl(w0, srcb + j),     w0b = __shfl(w0, srcb + j + 1);
            float w0c = __shfl(w0, srcb + j + 2), w0d = __shfl(w0, srcb + j + 3);
            float w1a = __shfl(w1, srcb + j),     w1b = __shfl(w1, srcb + j + 1);
            float w1c = __shfl(w1, srcb + j + 2), w1d = __shfl(w1, srcb + j + 3);
            u32x2 pa = ((const u32x2*)(o_in + (size_t)sa * 128))[l];
            u32x2 pb = ((const u32x2*)(o_in + (size_t)sb * 128))[l];
            u32x2 pc = ((const u32x2*)(o_in + (size_t)sc * 128))[l];
            u32x2 pd = ((const u32x2*)(o_in + (size_t)sd * 128))[l];
            float fa0 = bf2f((u16)(pa.x & 0xffff)), fa1 = bf2f((u16)(pa.x >> 16));
            float fa2 = bf2f((u16)(pa.y & 0xffff)), fa3 = bf2f((u16)(pa.y >> 16));
            float fb0 = bf2f((u16)(pb.x & 0xffff)), fb1 = bf2f((u16)(pb.x >> 16));
            float fb2 = bf2f((u16)(pb.y & 0xffff)), fb3 = bf2f((u16)(pb.y >> 16));
            float fc0 = bf2f((u16)(pc.x & 0xffff)), fc1 = bf2f((u16)(pc.x >> 16));
            float fc2 = bf2f((u16)(pc.y & 0xffff)), fc3 = bf2f((u16)(pc.y >> 16));
            float fd0 = bf2f((u16)(pd.x & 0xffff)), fd1 = bf2f((u16)(pd.x >> 16));
            float fd2 = bf2f((u16)(pd.y & 0xffff)), fd3 = bf2f((u16)(pd.y >> 16));
            a00 += w0a * fa0 + w0b * fb0 + w0c * fc0 + w0d * fd0;
            a01 += w0a * fa1 + w0b * fb1 + w0c * fc1 + w0d * fd1;
            a02 += w0a * fa2 + w0b * fb2 + w0c * fc2 + w0d * fd2;
            a03 += w0a * fa3 + w0b * fb3 + w0c * fc3 + w0d * fd3;
            a10 += w1a * fa0 + w1b * fb0 + w1c * fc0 + w1d * fd0;
            a11 += w1a * fa1 + w1b * fb1 + w1c * fc1 + w1d * fd1;
            a12 += w1a * fa2 + w1b * fb2 + w1c * fc2 + w1d * fd2;
            a13 += w1a * fa3 + w1b * fb3 + w1c * fc3 + w1d * fd3;
        }
        for (; j < cnt; ++j) {
            int sj = __shfl(s, srcb + j);
            float w0j = __shfl(w0, srcb + j), w1j = __shfl(w1, srcb + j);
            u32x2 pv = ((const u32x2*)(o_in + (size_t)sj * 128))[l];
            float f0 = bf2f((u16)(pv.x & 0xffff)), f1 = bf2f((u16)(pv.x >> 16));
            float f2 = bf2f((u16)(pv.y & 0xffff)), f3 = bf2f((u16)(pv.y >> 16));
            a00 += w0j * f0; a01 += w0j * f1; a02 += w0j * f2; a03 += w0j * f3;
            a10 += w1j * f0; a11 += w1j * f1; a12 += w1j * f2; a13 += w1j * f3;
        }
    }
#pragma unroll
    for (int off = 16; off; off >>= 1) { d0 += __shfl_xor(d0, off); d1 += __shfl_xor(d1, off); }
    float i0 = (d0 > 0.f) ? 1.f / d0 : 0.f, i1 = (d1 > 0.f) ? 1.f / d1 : 0.f;
    u32x2 p0, p1;
    p0.x = (u32)f2bf(a00 * i0) | ((u32)f2bf(a01 * i0) << 16);
    p0.y = (u32)f2bf(a02 * i0) | ((u32)f2bf(a03 * i0) << 16);
    p1.x = (u32)f2bf(a10 * i1) | ((u32)f2bf(a11 * i1) << 16);
    p1.y = (u32)f2bf(a12 * i1) | ((u32)f2bf(a13 * i1) << 16);
    u32x2* aw = (u32x2*)(agg + (size_t)node * 256);
    aw[l] = p0;           // head0 -> cols 0..127
    aw[32 + l] = p1;      // head1 -> cols 128..255
}

// ---------------- mean & var aggregation (interleaved featmv [N,64]), 2 nodes/wave + reparam ----------------
__global__ __launch_bounds__(256) void k_aggmv(const int* __restrict__ row_ptr, const int* __restrict__ esrc,
                                               const u16* __restrict__ featmv,
                                               const float* __restrict__ elm, const float* __restrict__ erm,
                                               const float* __restrict__ elv, const float* __restrict__ erv,
                                               const float* __restrict__ bm, const float* __restrict__ bv,
                                               const float* __restrict__ eps, float* __restrict__ out, int n) {
    __shared__ float wsm[256 * 4];
    __shared__ int ssm[256];
    int tid = threadIdx.x;
    int wave = tid >> 6, lane = tid & 63;
    int l = lane & 31;
    int node = blockIdx.x * 8 + wave * 2 + (lane >> 5);
    if (node >= n) node = n - 1;
    int tbl = l >> 4, h = (l >> 3) & 1;
    const int wtype = l >> 3;                     // 0..3 = m-h0, m-h1, v-h0, v-h1
    int beg = row_ptr[node], deg = row_ptr[node + 1] - beg;
    float erm0 = erm[2 * node], erm1 = erm[2 * node + 1];
    float erv0 = erv[2 * node], erv1 = erv[2 * node + 1];
    int degmax = max(deg, __shfl_xor(deg, 32));
    const int bidx = wave * 64 + (lane & 32);     // broadcaster base thread idx for this half
    float acc0 = 0.f, acc1 = 0.f;
    float dm0 = 0.f, dm1 = 0.f, dv0 = 0.f, dv1 = 0.f;
    for (int off0 = 0; off0 < degmax; off0 += 32) {
        float wm0 = 0.f, wm1 = 0.f, wv0 = 0.f, wv1 = 0.f; int s = 0;
        if (off0 + l < deg) {
            s = esrc[beg + off0 + l];
            float2 em = *(const float2*)(elm + 2 * s);
            float2 ev = *(const float2*)(elv + 2 * s);
            wm0 = expf(lrelu(em.x + erm0));
            wm1 = expf(lrelu(em.y + erm1));
            wv0 = expf(lrelu(ev.x + erv0));
            wv1 = expf(lrelu(ev.y + erv1));
        }
        dm0 += wm0; dm1 += wm1; dv0 += wv0; dv1 += wv1;
        f32x4 wq; wq[0] = wm0; wq[1] = wm1; wq[2] = wv0; wq[3] = wv1;
        *(f32x4*)&wsm[tid * 4] = wq;
        ssm[tid] = s;
        int cnt = min(32, degmax - off0);
        int j = 0;
        for (; j + 2 <= cnt; j += 2) {
            int sa = ssm[bidx + j], sb = ssm[bidx + j + 1];
            float wa = wsm[(bidx + j) * 4 + wtype];
            float wb = wsm[(bidx + j + 1) * 4 + wtype];
            u32 pa = ((const u32*)(featmv + (size_t)sa * 64))[l];
            u32 pb = ((const u32*)(featmv + (size_t)sb * 64))[l];
            acc0 += wa * bf2f((u16)(pa & 0xffff)) + wb * bf2f((u16)(pb & 0xffff));
            acc1 += wa * bf2f((u16)(pa >> 16)) + wb * bf2f((u16)(pb >> 16));
        }
        for (; j < cnt; ++j) {
            int sj = ssm[bidx + j];
            float wj = wsm[(bidx + j) * 4 + wtype];
            u32 pv = ((const u32*)(featmv + (size_t)sj * 64))[l];
            acc0 += wj * bf2f((u16)(pv & 0xffff));
            acc1 += wj * bf2f((u16)(pv >> 16));
        }
    }
#pragma unroll
    for (int off = 16; off; off >>= 1) {
        dm0 += __shfl_xor(dm0, off); dm1 += __shfl_xor(dm1, off);
        dv0 += __shfl_xor(dv0, off); dv1 += __shfl_xor(dv1, off);
    }
    float den = tbl ? (h ? dv1 : dv0) : (h ? dm1 : dm0);
    float inv = (den > 0.f) ? 1.f / den : 0.f;
    const int fidx0 = (2 * l) & 31;                 // table-local col (h*16 + f)
    float bias0 = tbl ? bv[fidx0] : bm[fidx0];
    float bias1 = tbl ? bv[fidx0 + 1] : bm[fidx0 + 1];
    float outc0 = acc0 * inv + bias0;
    float outc1 = acc1 * inv + bias1;
    // head-mean: lanes l and l^8 hold the same (tbl, f) pair for the two heads
    float hm0 = 0.5f * (outc0 + __shfl_xor(outc0, 8));
    float hm1 = 0.5f * (outc1 + __shfl_xor(outc1, 8));
    // var projections live on tbl=1 lanes (16..23 within half)
    int srcv = (lane & 32) + 16 + (l & 7);
    float vp0 = __shfl(hm0, srcv);
    float vp1 = __shfl(hm1, srcv);
    if (l < 8) {
        int f0 = 2 * l;
        float var0 = expf(vp0), var1 = expf(vp1);
        float2 e2 = *(const float2*)(eps + (size_t)node * 16 + f0);
        float z0 = hm0 + sqrtf(var0) * e2.x;
        float z1 = hm1 + sqrtf(var1) * e2.y;
        size_t base = (size_t)node * 16 + f0;
        *(float2*)(out + base) = make_float2(z0, z1);
        *(float2*)(out + (size_t)NNODES * 16 + base) = make_float2(hm0, hm1);
        *(float2*)(out + (size_t)2 * NNODES * 16 + base) = make_float2(var0, var1);
    }
}

// ---------------- host ----------------
extern "C" void kernel_launch(void* const* d_in, const int* in_sizes, int n_in,
                              void* d_out, int out_size, void* d_ws, size_t ws_size,
                              hipStream_t stream) {
    const int N = NNODES, E = NEDGES;
    const float* x   = (const float*)d_in[0];
    const int* src   = (const int*)d_in[1];
    const int* dst   = (const int*)d_in[2];
    const float* W1  = (const float*)d_in[3];
    const float* al1 = (const float*)d_in[4];
    const float* ar1 = (const float*)d_in[5];
    const float* b1  = (const float*)d_in[6];
    const float* W2  = (const float*)d_in[7];
    const float* al2 = (const float*)d_in[8];
    const float* ar2 = (const float*)d_in[9];
    const float* b2  = (const float*)d_in[10];
    const float* Wm  = (const float*)d_in[11];
    const float* alm = (const float*)d_in[12];
    const float* arm = (const float*)d_in[13];
    const float* bm  = (const float*)d_in[14];
    const float* Wv  = (const float*)d_in[15];
    const float* alv = (const float*)d_in[16];
    const float* arv = (const float*)d_in[17];
    const float* bv  = (const float*)d_in[18];
    const float* eps = (const float*)d_in[19];
    float* out = (float*)d_out;

    char* ws = (char*)d_ws;
    size_t off = 0;
    auto take = [&](size_t bytes) { size_t r = off; off += (bytes + 255) & ~(size_t)255; return r; };
    int* counts   = (int*)(ws + take((size_t)N * 4));
    int* cursor   = (int*)(ws + take((size_t)N * 4));
    int* row_ptr  = (int*)(ws + take((size_t)(N + 1) * 4));
    int* bsums    = (int*)(ws + take(256 * 4));
    int* esrc     = (int*)(ws + take((size_t)E * 4));
    u16* W1t      = (u16*)(ws + take((size_t)128 * 1000 * 2));
    u16* Wct      = (u16*)(ws + take((size_t)128 * 256 * 2));
    u16* Bmvt     = (u16*)(ws + take((size_t)64 * 128 * 2));
    float* ul2    = (float*)(ws + take(256 * 4));
    float* ur2    = (float*)(ws + take(256 * 4));
    float* bmean  = (float*)(ws + take(128 * 4));
    float* el1    = (float*)(ws + take((size_t)N * 4));
    float* er1    = (float*)(ws + take((size_t)N * 4));
    float* el2    = (float*)(ws + take((size_t)N * 2 * 4));
    float* er2    = (float*)(ws + take((size_t)N * 2 * 4));
    float* elm    = (float*)(ws + take((size_t)N * 2 * 4));
    float* erm    = (float*)(ws + take((size_t)N * 2 * 4));
    float* elv    = (float*)(ws + take((size_t)N * 2 * 4));
    float* erv    = (float*)(ws + take((size_t)N * 2 * 4));
    u16* o_bf     = (u16*)(ws + take((size_t)N * 128 * 2));
    u16* o2_bf    = (u16*)(ws + take((size_t)N * 128 * 2));
    u16* R        = (u16*)(ws + take((size_t)N * 256 * 2));
    u16* feat1    = R;          // layer-1 features [N,128]
    u16* agg      = R;          // layer-2 weighted aggregation of o [N,256] (after feat1 consumed)
    u16* featmv   = R;          // interleaved mv features [N,64] (after agg consumed)
    (void)ws_size; (void)n_in; (void)in_sizes; (void)out_size;

    const int nb = (N + 255) / 256;
    const int eb = (E + 255) / 256;
    const int wb8 = (N + 7) / 8;
    const int gb = (N + 63) / 64;

    // fused weight prep (independent of CSR)
    k_prep<<<dim3(630), 256, 0, stream>>>(W1, W2, Wm, Wv, al2, ar2, b2, W1t, Wct, Bmvt, ul2, ur2, bmean);

    // CSR build
    k_zero2<<<dim3(nb), 256, 0, stream>>>(counts, cursor, N);
    k_count<<<dim3(eb), 256, 0, stream>>>(dst, counts, E);
    k_scan1<<<dim3(nb), 256, 0, stream>>>(counts, row_ptr, bsums, N);
    k_scan2<<<dim3(1), 256, 0, stream>>>(bsums, nb);
    k_scan3<<<dim3(nb), 256, 0, stream>>>(row_ptr, bsums, N, E);
    k_fill<<<dim3(eb), 256, 0, stream>>>(src, dst, row_ptr, cursor, esrc, E);

    // layer 1 (A is f32): coalesced-A K-chunked GEMM + fused el1/er1
    k_gemm_tiled<float, 0><<<dim3(gb), 256, 0, stream>>>(x, W1t, feat1, N, 128, 1000,
                                                         nullptr, nullptr, al1, ar1, el1, er1);
    k_agg1<<<dim3(wb8), 256, 0, stream>>>(row_ptr, esrc, feat1, el1, er1, b1, ul2, ur2,
                                          o_bf, el2, er2, N);

    // layer 2: aggregate o; project+bias+residual in GEMM epilogue
    k_agg2o<<<dim3(wb8), 256, 0, stream>>>(row_ptr, esrc, o_bf, el2, er2, agg, N);
    k_gemm_tiled<u16, 1><<<dim3(gb), 256, 0, stream>>>(agg, Wct, o2_bf, N, 128, 256,
                                                       bmean, o_bf, nullptr, nullptr, nullptr, nullptr);

    // mean/var: single fused GEMM (m|v) + fused logits
    k_gemmmv<<<dim3(N / 16), 64, 0, stream>>>(o2_bf, Bmvt, featmv, alm, arm, alv, arv,
                                              elm, erm, elv, erv, N);
    k_aggmv<<<dim3(wb8), 256, 0, stream>>>(row_ptr, esrc, featmv, elm, erm, elv, erv,
                                           bm, bv, eps, out, N);
}